// Round 7
// baseline (144.817 us; speedup 1.0000x reference)
//
#include <hip/hip_runtime.h>
#include <hip/hip_bf16.h>

#define NROW 4096
#define KDIM 2048
#define ROWB (KDIM * 2)     // bytes per Xb row
#define BT 256              // block tile (M = N)
#define BK 64               // k-tile depth (128 bytes)
#define NKT (KDIM / BK)     // 32 k-tiles
#define ITERS (NKT / 2)     // 16 iterations, 2 k-tiles each
#define LDSBUF 65536        // per k-tile: A 32 KB + B 32 KB
#define PHI(r) (((r) & 7) << 4)

typedef __attribute__((ext_vector_type(8))) short bf16x8;
typedef __attribute__((ext_vector_type(4))) float f32x4;
typedef __attribute__((ext_vector_type(4))) unsigned short u16x4;

#define MFMA16(a, b, c) __builtin_amdgcn_mfma_f32_16x16x32_bf16((a), (b), (c), 0, 0, 0)

__device__ __forceinline__ unsigned short f2bf(float x) {
    unsigned u = __float_as_uint(x);
    unsigned r = (u + 0x7FFFu + ((u >> 16) & 1u)) >> 16;
    return (unsigned short)r;
}
__device__ __forceinline__ float bf2f(unsigned short b) {
    return __uint_as_float(((unsigned)b) << 16);
}

// Kernel 1: fp32 -> bf16 copy + row sum-of-squares from the bf16 values.
__global__ __launch_bounds__(256) void k_convert(const float* __restrict__ X,
                                                 unsigned short* __restrict__ Xb,
                                                 float* __restrict__ sqv) {
    const int row = blockIdx.x;
    const int t = threadIdx.x;
    const float4* xr = (const float4*)(X + (size_t)row * KDIM);
    unsigned short* br = Xb + (size_t)row * KDIM;
    float acc = 0.f;
#pragma unroll
    for (int it = 0; it < 2; ++it) {
        int idx = t * 2 + it;
        float4 v = xr[idx];
        u16x4 b;
        b.x = f2bf(v.x); b.y = f2bf(v.y); b.z = f2bf(v.z); b.w = f2bf(v.w);
        float f0 = bf2f(b.x), f1 = bf2f(b.y), f2 = bf2f(b.z), f3 = bf2f(b.w);
        acc += f0 * f0 + f1 * f1 + f2 * f2 + f3 * f3;
        *(u16x4*)(br + idx * 4) = b;
    }
#pragma unroll
    for (int s = 32; s > 0; s >>= 1) acc += __shfl_xor(acc, s);
    __shared__ float red[4];
    const int lane = t & 63, wid = t >> 6;
    if (lane == 0) red[wid] = acc;
    __syncthreads();
    if (t == 0) sqv[row] = red[0] + red[1] + red[2] + red[3];
}

// Kernel 2: init per-row accumulators + zero the output scalar.
__global__ __launch_bounds__(256) void k_init(unsigned* hp, unsigned* hn,
                                              unsigned* mor, unsigned* mir,
                                              int* anyor, float* out) {
    int i = blockIdx.x * 256 + threadIdx.x;
    hp[i] = 0u;
    hn[i] = 0x7F800000u;
    mor[i] = 0u;
    mir[i] = 0x7F800000u;
    anyor[i] = 0;
    if (i == 0) out[0] = 0.f;
}

// Kernel 3: 256x256 Gram GEMM, m201-faithful 8-phase schedule.
// Iteration = 2 K-tiles (kt0 even -> buf0, kt1 odd -> buf1). Each phase:
// [ds_read this quadrant's operands; stage half-tile; SB0; s_barrier;
//  lgkmcnt(0); SB0; setprio(1); 16 MFMA; setprio(0); SB0; s_barrier].
// Between the two barriers waves diverge (reads drain at different times)
// -> cross-wave LDS||MFMA overlap; setprio arbitrates the role-split.
// Staging placed in race-free phases: P5 A->buf0 (last buf0-A read: P3),
// P6 B->buf0 (last read P2), P7 B->buf1 (last read P6), P8 A->buf1 (last
// read P7). vmcnt(8)@P8 = next kt0 resident, kt1 stays in flight;
// vmcnt(0)@P4 drains 4-phase-old kt1 loads. Source-side XOR swizzle.
__global__ __launch_bounds__(512, 2) void k_gemm(const unsigned short* __restrict__ Xb,
                                                 const float* __restrict__ sqv,
                                                 const int* __restrict__ ta,
                                                 const int* __restrict__ tb,
                                                 unsigned int* __restrict__ hp,
                                                 unsigned int* __restrict__ hn,
                                                 unsigned int* __restrict__ mor,
                                                 unsigned int* __restrict__ mir,
                                                 int* __restrict__ anyor) {
    __shared__ char lds[2 * LDSBUF];  // buf0 = even k-tiles, buf1 = odd
    const int bi = blockIdx.x >> 4;
    const int bj = blockIdx.x & 15;
    const int t = threadIdx.x;
    const int lane = t & 63;
    const int w = t >> 6;        // wave 0..7
    const int wm = w >> 2;       // 0..1  (128-row half of A)
    const int wn = w & 3;        // 0..3  (64-col quarter of B)
    const int l15 = lane & 15;
    const int kg16 = (lane >> 4) * 16;
    const char* xbase = (const char*)Xb;

    const int P = (l15 & 7) << 4;
    int akb[2], bkb[2];
#pragma unroll
    for (int ks = 0; ks < 2; ++ks) {
        const int kx = (ks * 64 + kg16) ^ P;
        akb[ks] = (wm * 128 + l15) * 128 + kx;
        bkb[ks] = 32768 + (wn * 64 + l15) * 128 + kx;
    }

    f32x4 acc[8][4] = {};

    // Stage one half-tile (128 rows x 128 B) of k-tile kt_: 2 gload instrs,
    // thread t covers row q*64+(t>>3), 16B col (t&7). Linear LDS dest,
    // swizzle on the global source (rule #21).
#define STAGEH(kt_, isb_, hh_)                                                \
    do {                                                                      \
        _Pragma("unroll")                                                     \
        for (int q_ = 0; q_ < 2; ++q_) {                                      \
            const int row_ = (hh_) * 128 + q_ * 64 + (t >> 3);                \
            const int gr_ = ((isb_) ? bj : bi) * BT + row_;                   \
            const char* gsrc_ = xbase + (size_t)gr_ * ROWB +                  \
                                (size_t)(kt_) * 128 +                         \
                                (((t & 7) * 16) ^ PHI(row_));                 \
            char* ldst_ = lds + ((kt_) & 1) * LDSBUF + (isb_) * 32768 +       \
                          row_ * 128 + (t & 7) * 16;                          \
            __builtin_amdgcn_global_load_lds(                                 \
                (const __attribute__((address_space(1))) void*)gsrc_,         \
                (__attribute__((address_space(3))) void*)ldst_, 16, 0, 0);    \
        }                                                                     \
    } while (0)

#define SYNC_PRE                                                              \
    __builtin_amdgcn_sched_barrier(0);                                        \
    __builtin_amdgcn_s_barrier();                                             \
    asm volatile("s_waitcnt lgkmcnt(0)" ::: "memory");                        \
    __builtin_amdgcn_sched_barrier(0);                                        \
    __builtin_amdgcn_s_setprio(1);

#define SYNC_POST                                                             \
    __builtin_amdgcn_s_setprio(0);                                            \
    __builtin_amdgcn_sched_barrier(0);                                        \
    __builtin_amdgcn_s_barrier();

    // prologue: stage k-tiles 0 (A,B) then 1 (A,B); kt0 resident, kt1 in flight
    STAGEH(0, 0, 0); STAGEH(0, 0, 1); STAGEH(0, 1, 0); STAGEH(0, 1, 1);
    STAGEH(1, 0, 0); STAGEH(1, 0, 1); STAGEH(1, 1, 0); STAGEH(1, 1, 1);
    asm volatile("s_waitcnt vmcnt(8)" ::: "memory");
    __builtin_amdgcn_s_barrier();

    bf16x8 af0[4][2], af1[4][2], b01[2][2], b23[2][2];
    const char* buf0 = lds;
    const char* buf1 = lds + LDSBUF;

    for (int it = 0; it < ITERS; ++it) {
        const int nk0 = (2 * it + 2) & (NKT - 1);  // staged even k-tile (wraps)
        const int nk1 = (2 * it + 3) & (NKT - 1);  // staged odd k-tile

        // ---- P1: read af0(kt0)+b01(kt0) [12]; MFMA q00(kt0)
#pragma unroll
        for (int ks = 0; ks < 2; ++ks) {
#pragma unroll
            for (int m = 0; m < 4; ++m)
                af0[m][ks] = *(const bf16x8*)(buf0 + akb[ks] + m * 2048);
            b01[0][ks] = *(const bf16x8*)(buf0 + bkb[ks]);
            b01[1][ks] = *(const bf16x8*)(buf0 + bkb[ks] + 2048);
        }
        SYNC_PRE
#pragma unroll
        for (int ks = 0; ks < 2; ++ks)
#pragma unroll
            for (int m = 0; m < 4; ++m) {
                acc[m][0] = MFMA16(af0[m][ks], b01[0][ks], acc[m][0]);
                acc[m][1] = MFMA16(af0[m][ks], b01[1][ks], acc[m][1]);
            }
        SYNC_POST

        // ---- P2: read b23(kt0) [4]; MFMA q01(kt0)
#pragma unroll
        for (int ks = 0; ks < 2; ++ks) {
            b23[0][ks] = *(const bf16x8*)(buf0 + bkb[ks] + 2 * 2048);
            b23[1][ks] = *(const bf16x8*)(buf0 + bkb[ks] + 3 * 2048);
        }
        SYNC_PRE
#pragma unroll
        for (int ks = 0; ks < 2; ++ks)
#pragma unroll
            for (int m = 0; m < 4; ++m) {
                acc[m][2] = MFMA16(af0[m][ks], b23[0][ks], acc[m][2]);
                acc[m][3] = MFMA16(af0[m][ks], b23[1][ks], acc[m][3]);
            }
        SYNC_POST

        // ---- P3: read af1(kt0) [8]; MFMA q11(kt0)
#pragma unroll
        for (int ks = 0; ks < 2; ++ks)
#pragma unroll
            for (int m = 0; m < 4; ++m)
                af1[m][ks] = *(const bf16x8*)(buf0 + akb[ks] + (4 + m) * 2048);
        SYNC_PRE
#pragma unroll
        for (int ks = 0; ks < 2; ++ks)
#pragma unroll
            for (int m = 0; m < 4; ++m) {
                acc[4 + m][2] = MFMA16(af1[m][ks], b23[0][ks], acc[4 + m][2]);
                acc[4 + m][3] = MFMA16(af1[m][ks], b23[1][ks], acc[4 + m][3]);
            }
        SYNC_POST

        // ---- P4: no reads; drain old kt1 loads; MFMA q10(kt0)
        asm volatile("s_waitcnt vmcnt(0)" ::: "memory");
        SYNC_PRE
#pragma unroll
        for (int ks = 0; ks < 2; ++ks)
#pragma unroll
            for (int m = 0; m < 4; ++m) {
                acc[4 + m][0] = MFMA16(af1[m][ks], b01[0][ks], acc[4 + m][0]);
                acc[4 + m][1] = MFMA16(af1[m][ks], b01[1][ks], acc[4 + m][1]);
            }
        SYNC_POST

        // ---- P5: read af0(kt1)+b01(kt1) [12]; stage A(nk0)->buf0; q00(kt1)
#pragma unroll
        for (int ks = 0; ks < 2; ++ks) {
#pragma unroll
            for (int m = 0; m < 4; ++m)
                af0[m][ks] = *(const bf16x8*)(buf1 + akb[ks] + m * 2048);
            b01[0][ks] = *(const bf16x8*)(buf1 + bkb[ks]);
            b01[1][ks] = *(const bf16x8*)(buf1 + bkb[ks] + 2048);
        }
        STAGEH(nk0, 0, 0); STAGEH(nk0, 0, 1);
        SYNC_PRE
#pragma unroll
        for (int ks = 0; ks < 2; ++ks)
#pragma unroll
            for (int m = 0; m < 4; ++m) {
                acc[m][0] = MFMA16(af0[m][ks], b01[0][ks], acc[m][0]);
                acc[m][1] = MFMA16(af0[m][ks], b01[1][ks], acc[m][1]);
            }
        SYNC_POST

        // ---- P6: read b23(kt1) [4]; stage B(nk0)->buf0; q01(kt1)
#pragma unroll
        for (int ks = 0; ks < 2; ++ks) {
            b23[0][ks] = *(const bf16x8*)(buf1 + bkb[ks] + 2 * 2048);
            b23[1][ks] = *(const bf16x8*)(buf1 + bkb[ks] + 3 * 2048);
        }
        STAGEH(nk0, 1, 0); STAGEH(nk0, 1, 1);
        SYNC_PRE
#pragma unroll
        for (int ks = 0; ks < 2; ++ks)
#pragma unroll
            for (int m = 0; m < 4; ++m) {
                acc[m][2] = MFMA16(af0[m][ks], b23[0][ks], acc[m][2]);
                acc[m][3] = MFMA16(af0[m][ks], b23[1][ks], acc[m][3]);
            }
        SYNC_POST

        // ---- P7: read af1(kt1) [8]; stage B(nk1)->buf1 (B last read P6); q11(kt1)
#pragma unroll
        for (int ks = 0; ks < 2; ++ks)
#pragma unroll
            for (int m = 0; m < 4; ++m)
                af1[m][ks] = *(const bf16x8*)(buf1 + akb[ks] + (4 + m) * 2048);
        STAGEH(nk1, 1, 0); STAGEH(nk1, 1, 1);
        SYNC_PRE
#pragma unroll
        for (int ks = 0; ks < 2; ++ks)
#pragma unroll
            for (int m = 0; m < 4; ++m) {
                acc[4 + m][2] = MFMA16(af1[m][ks], b23[0][ks], acc[4 + m][2]);
                acc[4 + m][3] = MFMA16(af1[m][ks], b23[1][ks], acc[4 + m][3]);
            }
        SYNC_POST

        // ---- P8: stage A(nk1)->buf1 (A last read P7); vmcnt(8): nk0 resident,
        //          nk1's 8 loads stay in flight; MFMA q10(kt1)
        STAGEH(nk1, 0, 0); STAGEH(nk1, 0, 1);
        asm volatile("s_waitcnt vmcnt(8)" ::: "memory");
        SYNC_PRE
#pragma unroll
        for (int ks = 0; ks < 2; ++ks)
#pragma unroll
            for (int m = 0; m < 4; ++m) {
                acc[4 + m][0] = MFMA16(af1[m][ks], b01[0][ks], acc[4 + m][0]);
                acc[4 + m][1] = MFMA16(af1[m][ks], b01[1][ks], acc[4 + m][1]);
            }
        SYNC_POST
    }
    asm volatile("s_waitcnt vmcnt(0)" ::: "memory");  // drain wrap stages
#undef STAGEH
#undef SYNC_PRE
#undef SYNC_POST

    // ---- epilogue: dist + masks + row-side reductions ----
    float sqj[4];
    int taj[4], tbj[4];
#pragma unroll
    for (int n = 0; n < 4; ++n) {
        int j = bj * BT + wn * 64 + n * 16 + l15;
        sqj[n] = sqv[j];
        taj[n] = ta[j];
        tbj[n] = tb[j];
    }
    const float INF = __uint_as_float(0x7F800000u);
#pragma unroll
    for (int m = 0; m < 8; ++m) {
#pragma unroll
        for (int reg = 0; reg < 4; ++reg) {
            const int i = bi * BT + wm * 128 + m * 16 + (lane >> 4) * 4 + reg;
            const float sqi = sqv[i];
            const int tai = ta[i], tbi = tb[i];
            float vhp = 0.f, vhn = INF, vmor = 0.f, vmir = INF, vany = 0.f;
#pragma unroll
            for (int n = 0; n < 4; ++n) {
                float d2 = sqi + sqj[n] - 2.f * acc[m][n][reg];
                float d = sqrtf(fmaxf(d2, 1e-12f));
                bool ma = (tai == taj[n]), mb = (tbi == tbj[n]);
                if (ma && mb) {
                    vhp = fmaxf(vhp, d);
                } else if (ma != mb) {
                    vmor = fmaxf(vmor, d);
                    vmir = fminf(vmir, d);
                    vany = 1.f;
                } else {
                    vhn = fminf(vhn, d);
                }
            }
#pragma unroll
            for (int s = 1; s < 16; s <<= 1) {
                vhp = fmaxf(vhp, __shfl_xor(vhp, s, 16));
                vhn = fminf(vhn, __shfl_xor(vhn, s, 16));
                vmor = fmaxf(vmor, __shfl_xor(vmor, s, 16));
                vmir = fminf(vmir, __shfl_xor(vmir, s, 16));
                vany = fmaxf(vany, __shfl_xor(vany, s, 16));
            }
            if (l15 == 0) {
                if (vhp > 0.f) atomicMax(&hp[i], __float_as_uint(vhp));
                if (vhn < INF) atomicMin(&hn[i], __float_as_uint(vhn));
                if (vany > 0.f) {
                    atomicMax(&mor[i], __float_as_uint(vmor));
                    atomicMin(&mir[i], __float_as_uint(vmir));
                    atomicOr(&anyor[i], 1);
                }
            }
        }
    }
}

// Kernel 4: final scalar loss (16 blocks, one row per thread, atomicAdd).
__global__ __launch_bounds__(256) void k_final(const unsigned* __restrict__ hp,
                                               const unsigned* __restrict__ hn,
                                               const unsigned* __restrict__ mor,
                                               const unsigned* __restrict__ mir,
                                               const int* __restrict__ anyor,
                                               const int* __restrict__ epoch_p,
                                               float* __restrict__ out) {
    const int t = threadIdx.x;
    const int i = blockIdx.x * 256 + t;
    const bool eok = (*epoch_p > 50);
    float fhp = __uint_as_float(hp[i]);
    float fhn = __uint_as_float(hn[i]);
    bool use_or = (anyor[i] != 0) && eok;
    float sp = use_or ? __uint_as_float(mor[i]) : fhp;
    float sn = use_or ? __uint_as_float(mir[i]) : fhn;
    float s = fmaxf(0.f, fhp - fhn + 0.3f) + fmaxf(0.f, sp - fhn + 0.3f) +
              fmaxf(0.f, fhp - sn + 0.3f);
#pragma unroll
    for (int sh = 32; sh > 0; sh >>= 1) s += __shfl_xor(s, sh);
    __shared__ float red[4];
    const int lane = t & 63, wid = t >> 6;
    if (lane == 0) red[wid] = s;
    __syncthreads();
    if (t == 0)
        atomicAdd(out, (red[0] + red[1] + red[2] + red[3]) * (1.f / 4096.f));
}

extern "C" void kernel_launch(void* const* d_in, const int* in_sizes, int n_in,
                              void* d_out, int out_size, void* d_ws, size_t ws_size,
                              hipStream_t stream) {
    const float* X = (const float*)d_in[0];
    const int* ta = (const int*)d_in[1];
    const int* tb = (const int*)d_in[2];
    const int* epoch_p = (const int*)d_in[4];
    float* out = (float*)d_out;

    char* ws = (char*)d_ws;
    unsigned short* Xb = (unsigned short*)ws;  // 16 MB bf16 copy
    size_t off = (size_t)NROW * KDIM * sizeof(unsigned short);
    float* sqv = (float*)(ws + off); off += (size_t)NROW * 4;
    unsigned* hp = (unsigned*)(ws + off); off += (size_t)NROW * 4;
    unsigned* hn = (unsigned*)(ws + off); off += (size_t)NROW * 4;
    unsigned* mor = (unsigned*)(ws + off); off += (size_t)NROW * 4;
    unsigned* mir = (unsigned*)(ws + off); off += (size_t)NROW * 4;
    int* anyor = (int*)(ws + off); off += (size_t)NROW * 4;

    k_convert<<<NROW, 256, 0, stream>>>(X, Xb, sqv);
    k_init<<<NROW / 256, 256, 0, stream>>>(hp, hn, mor, mir, anyor, out);
    k_gemm<<<(NROW / BT) * (NROW / BT), 512, 0, stream>>>(Xb, sqv, ta, tb,
                                                          hp, hn, mor, mir, anyor);
    k_final<<<NROW / 256, 256, 0, stream>>>(hp, hn, mor, mir, anyor, epoch_p, out);
}

// Round 8
// 100.273 us; speedup vs baseline: 1.4442x; 1.4442x over previous
//
#include <hip/hip_runtime.h>
#include <hip/hip_bf16.h>

#define NROW 4096
#define KDIM 2048
#define ROWB (KDIM * 2)     // bytes per Xb row
#define BT 256              // block tile (M = N)
#define BK 32               // k-tile depth (64 bytes)
#define NT (KDIM / BK)      // 64 k-tiles
#define KTBUF 32768         // per k-tile: A 16 KB + B 16 KB
#define AB_OFF 16384
#define PHI(r) ((((r) >> 1) & 3) << 4)   // round-3 verified: 0 bank conflicts

typedef __attribute__((ext_vector_type(8))) short bf16x8;
typedef __attribute__((ext_vector_type(4))) float f32x4;
typedef __attribute__((ext_vector_type(4))) unsigned short u16x4;

#define MFMA16(a, b, c) __builtin_amdgcn_mfma_f32_16x16x32_bf16((a), (b), (c), 0, 0, 0)

__device__ __forceinline__ unsigned short f2bf(float x) {
    unsigned u = __float_as_uint(x);
    unsigned r = (u + 0x7FFFu + ((u >> 16) & 1u)) >> 16;
    return (unsigned short)r;
}
__device__ __forceinline__ float bf2f(unsigned short b) {
    return __uint_as_float(((unsigned)b) << 16);
}

// Kernel 1: fp32 -> bf16 copy + row sum-of-squares from the bf16 values.
__global__ __launch_bounds__(256) void k_convert(const float* __restrict__ X,
                                                 unsigned short* __restrict__ Xb,
                                                 float* __restrict__ sqv) {
    const int row = blockIdx.x;
    const int t = threadIdx.x;
    const float4* xr = (const float4*)(X + (size_t)row * KDIM);
    unsigned short* br = Xb + (size_t)row * KDIM;
    float acc = 0.f;
#pragma unroll
    for (int it = 0; it < 2; ++it) {
        int idx = t * 2 + it;
        float4 v = xr[idx];
        u16x4 b;
        b.x = f2bf(v.x); b.y = f2bf(v.y); b.z = f2bf(v.z); b.w = f2bf(v.w);
        float f0 = bf2f(b.x), f1 = bf2f(b.y), f2 = bf2f(b.z), f3 = bf2f(b.w);
        acc += f0 * f0 + f1 * f1 + f2 * f2 + f3 * f3;
        *(u16x4*)(br + idx * 4) = b;
    }
#pragma unroll
    for (int s = 32; s > 0; s >>= 1) acc += __shfl_xor(acc, s);
    __shared__ float red[4];
    const int lane = t & 63, wid = t >> 6;
    if (lane == 0) red[wid] = acc;
    __syncthreads();
    if (t == 0) sqv[row] = red[0] + red[1] + red[2] + red[3];
}

// Kernel 2: init per-row accumulators (d^2-space) + zero the output scalar.
__global__ __launch_bounds__(256) void k_init(unsigned* hp, unsigned* hn,
                                              unsigned* mor, unsigned* mir,
                                              float* out) {
    int i = blockIdx.x * 256 + threadIdx.x;
    hp[i] = 0u;
    hn[i] = 0x7F800000u;
    mor[i] = 0u;
    mir[i] = 0x7F800000u;
    if (i == 0) out[0] = 0.f;
}

// Kernel 3: 256x256 Gram GEMM. Minimal-sync K-step: per K-tile exactly
//   [vmcnt(4); s_barrier; 12 ds_read_b128; stage tile t+2 (4 gload_lds);
//    32 MFMA]
// 3 LDS buffers (96 KiB) so staging runs 2 tiles ahead and vmcnt never
// drains mid-loop. Reads are issued BEFORE the global_load_lds of the same
// region so no conservative write->read LDS ordering can stall them.
// The compiler is left free to interleave lgkm waits with the MFMA cluster.
// Source-side XOR swizzle (rule #21), PHI verified 0-conflict in round 3.
// Epilogue reduces in d^2 space (sqrt deferred, monotone), 4 chains only.
__global__ __launch_bounds__(512, 2) void k_gemm(const unsigned short* __restrict__ Xb,
                                                 const float* __restrict__ sqv,
                                                 const int* __restrict__ ta,
                                                 const int* __restrict__ tb,
                                                 unsigned int* __restrict__ hp,
                                                 unsigned int* __restrict__ hn,
                                                 unsigned int* __restrict__ mor,
                                                 unsigned int* __restrict__ mir) {
    __shared__ char lds[3 * KTBUF];  // 96 KiB
    const int bi = blockIdx.x >> 4;
    const int bj = blockIdx.x & 15;
    const int t = threadIdx.x;
    const int lane = t & 63;
    const int w = t >> 6;        // wave 0..7
    const int wm = w >> 2;       // 0..1  (128-row half of A)
    const int wn = w & 3;        // 0..3  (64-col quarter of B)
    const int l15 = lane & 15;
    const int kg16 = (lane >> 4) * 16;  // k-group 16B slot within 64B row
    const char* xbase = (const char*)Xb;

    // ds_read bases. (r>>1)&3 == (l15>>1)&3 for all frag rows (row offsets
    // are multiples of 16) -> swizzle is lane-constant, folds into the base.
    const int swz = ((l15 >> 1) & 3) << 4;
    const int akbase = (wm * 128 + l15) * 64 + (kg16 ^ swz);
    const int bkbase = AB_OFF + (wn * 64 + l15) * 64 + (kg16 ^ swz);

    f32x4 acc[8][4] = {};

    // Stage k-tile tt into buffer sb3 (4 gload_lds per thread: A q0,q1 + B
    // q0,q1). Wave-linear LDS dest (base + lane*16); swizzle on the global
    // source column.
#define STAGE(tt, sb3)                                                        \
    do {                                                                      \
        _Pragma("unroll")                                                     \
        for (int isb_ = 0; isb_ < 2; ++isb_) {                                \
            _Pragma("unroll")                                                 \
            for (int q_ = 0; q_ < 2; ++q_) {                                  \
                const int row_ = q_ * 128 + (t >> 2);                         \
                const int gr_ = (isb_ ? bj : bi) * BT + row_;                 \
                const char* gsrc_ = xbase + (size_t)gr_ * ROWB +              \
                                    (size_t)(tt) * 64 +                       \
                                    (((t & 3) * 16) ^ PHI(row_));             \
                char* ldst_ = lds + (sb3) * KTBUF + isb_ * AB_OFF +           \
                              row_ * 64 + (t & 3) * 16;                       \
                __builtin_amdgcn_global_load_lds(                             \
                    (const __attribute__((address_space(1))) void*)gsrc_,     \
                    (__attribute__((address_space(3))) void*)ldst_, 16, 0, 0);\
            }                                                                 \
        }                                                                     \
    } while (0)

    // prologue: tiles 0 -> buf0, 1 -> buf1 (8 loads/thread outstanding)
    STAGE(0, 0);
    STAGE(1, 1);

    int r3 = 0, s3 = 2;  // read buffer, stage buffer (t+2)
    for (int tk = 0; tk < NT; ++tk) {
        if (tk < NT - 1)
            asm volatile("s_waitcnt vmcnt(4)" ::: "memory");  // buf r3 resident
        else
            asm volatile("s_waitcnt vmcnt(0)" ::: "memory");
        __builtin_amdgcn_s_barrier();

        const char* buf = lds + r3 * KTBUF;
        // ---- all fragment reads first (issue before any LDS-writing vmem)
        bf16x8 af[8], bfr[4];
#pragma unroll
        for (int m = 0; m < 8; ++m)
            af[m] = *(const bf16x8*)(buf + akbase + m * 1024);
#pragma unroll
        for (int n = 0; n < 4; ++n)
            bfr[n] = *(const bf16x8*)(buf + bkbase + n * 1024);

        // ---- stage tile tk+2 into buf s3 (WAR-safe: that buffer's reads
        // finished before the barrier above)
        if (tk + 2 < NT) STAGE(tk + 2, s3);

        // ---- 32 MFMA; compiler inserts fine-grained lgkm waits
#pragma unroll
        for (int m = 0; m < 8; ++m)
#pragma unroll
            for (int n = 0; n < 4; ++n)
                acc[m][n] = MFMA16(af[m], bfr[n], acc[m][n]);

        r3 = (r3 == 2) ? 0 : r3 + 1;
        s3 = (s3 == 2) ? 0 : s3 + 1;
    }
#undef STAGE

    // ---- epilogue: d^2 + masks + row-side reductions (d^2-space) ----
    float sqj[4];
    int taj[4], tbj[4];
#pragma unroll
    for (int n = 0; n < 4; ++n) {
        int j = bj * BT + wn * 64 + n * 16 + l15;
        sqj[n] = sqv[j];
        taj[n] = ta[j];
        tbj[n] = tb[j];
    }
    const float INF = __uint_as_float(0x7F800000u);
#pragma unroll
    for (int m = 0; m < 8; ++m) {
#pragma unroll
        for (int reg = 0; reg < 4; ++reg) {
            const int i = bi * BT + wm * 128 + m * 16 + (lane >> 4) * 4 + reg;
            const float sqi = sqv[i];
            const int tai = ta[i], tbi = tb[i];
            float vhp = 0.f, vhn = INF, vmo = 0.f, vmi = INF;
#pragma unroll
            for (int n = 0; n < 4; ++n) {
                float d2 = fmaxf(sqi + sqj[n] - 2.f * acc[m][n][reg], 1e-12f);
                bool ma = (tai == taj[n]), mb = (tbi == tbj[n]);
                if (ma && mb) {
                    vhp = fmaxf(vhp, d2);
                } else if (ma != mb) {
                    vmo = fmaxf(vmo, d2);
                    vmi = fminf(vmi, d2);
                } else {
                    vhn = fminf(vhn, d2);
                }
            }
#pragma unroll
            for (int s = 1; s < 16; s <<= 1) {
                vhp = fmaxf(vhp, __shfl_xor(vhp, s, 16));
                vhn = fminf(vhn, __shfl_xor(vhn, s, 16));
                vmo = fmaxf(vmo, __shfl_xor(vmo, s, 16));
                vmi = fminf(vmi, __shfl_xor(vmi, s, 16));
            }
            if (l15 == 0) {
                if (vhp > 0.f) atomicMax(&hp[i], __float_as_uint(vhp));
                if (vhn < INF) atomicMin(&hn[i], __float_as_uint(vhn));
                if (vmo > 0.f) {
                    atomicMax(&mor[i], __float_as_uint(vmo));
                    atomicMin(&mir[i], __float_as_uint(vmi));
                }
            }
        }
    }
}

// Kernel 4: final scalar loss (sqrt applied here; mor!=0 is the or-flag).
__global__ __launch_bounds__(256) void k_final(const unsigned* __restrict__ hp,
                                               const unsigned* __restrict__ hn,
                                               const unsigned* __restrict__ mor,
                                               const unsigned* __restrict__ mir,
                                               const int* __restrict__ epoch_p,
                                               float* __restrict__ out) {
    const int t = threadIdx.x;
    const int i = blockIdx.x * 256 + t;
    const bool eok = (*epoch_p > 50);
    const unsigned morb = mor[i];
    float fhp = sqrtf(__uint_as_float(hp[i]));
    float fhn = sqrtf(__uint_as_float(hn[i]));
    bool use_or = (morb != 0u) && eok;
    float sp = use_or ? sqrtf(__uint_as_float(morb)) : fhp;
    float sn = use_or ? sqrtf(__uint_as_float(mir[i])) : fhn;
    float s = fmaxf(0.f, fhp - fhn + 0.3f) + fmaxf(0.f, sp - fhn + 0.3f) +
              fmaxf(0.f, fhp - sn + 0.3f);
#pragma unroll
    for (int sh = 32; sh > 0; sh >>= 1) s += __shfl_xor(s, sh);
    __shared__ float red[4];
    const int lane = t & 63, wid = t >> 6;
    if (lane == 0) red[wid] = s;
    __syncthreads();
    if (t == 0)
        atomicAdd(out, (red[0] + red[1] + red[2] + red[3]) * (1.f / 4096.f));
}

extern "C" void kernel_launch(void* const* d_in, const int* in_sizes, int n_in,
                              void* d_out, int out_size, void* d_ws, size_t ws_size,
                              hipStream_t stream) {
    const float* X = (const float*)d_in[0];
    const int* ta = (const int*)d_in[1];
    const int* tb = (const int*)d_in[2];
    const int* epoch_p = (const int*)d_in[4];
    float* out = (float*)d_out;

    char* ws = (char*)d_ws;
    unsigned short* Xb = (unsigned short*)ws;  // 16 MB bf16 copy
    size_t off = (size_t)NROW * KDIM * sizeof(unsigned short);
    float* sqv = (float*)(ws + off); off += (size_t)NROW * 4;
    unsigned* hp = (unsigned*)(ws + off); off += (size_t)NROW * 4;
    unsigned* hn = (unsigned*)(ws + off); off += (size_t)NROW * 4;
    unsigned* mor = (unsigned*)(ws + off); off += (size_t)NROW * 4;
    unsigned* mir = (unsigned*)(ws + off); off += (size_t)NROW * 4;

    k_convert<<<NROW, 256, 0, stream>>>(X, Xb, sqv);
    k_init<<<NROW / 256, 256, 0, stream>>>(hp, hn, mor, mir, out);
    k_gemm<<<(NROW / BT) * (NROW / BT), 512, 0, stream>>>(Xb, sqv, ta, tb,
                                                          hp, hn, mor, mir);
    k_final<<<NROW / 256, 256, 0, stream>>>(hp, hn, mor, mir, epoch_p, out);
}

// Round 9
// 93.114 us; speedup vs baseline: 1.5553x; 1.0769x over previous
//
#include <hip/hip_runtime.h>
#include <hip/hip_bf16.h>

#define NROW 4096
#define KDIM 2048
#define ROWB (KDIM * 2)     // bytes per Xb row
#define BT 128              // block tile (M = N)
#define NB (NROW / BT)      // 32 block-rows; triangle grid = 528
#define BK 32               // k-tile depth (64 bytes)
#define NT (KDIM / BK)      // 64 k-tiles
#define KTBUF 16384         // per k-tile: A 8 KB + B 8 KB
#define AB_OFF 8192
#define PHI(r) ((((r) >> 1) & 3) << 4)   // verified 0 bank conflicts (r3/r8)

typedef __attribute__((ext_vector_type(8))) short bf16x8;
typedef __attribute__((ext_vector_type(4))) float f32x4;
typedef __attribute__((ext_vector_type(4))) unsigned short u16x4;

#define MFMA16(a, b, c) __builtin_amdgcn_mfma_f32_16x16x32_bf16((a), (b), (c), 0, 0, 0)

__device__ __forceinline__ unsigned short f2bf(float x) {
    unsigned u = __float_as_uint(x);
    unsigned r = (u + 0x7FFFu + ((u >> 16) & 1u)) >> 16;
    return (unsigned short)r;
}
__device__ __forceinline__ float bf2f(unsigned short b) {
    return __uint_as_float(((unsigned)b) << 16);
}

// Kernel 1: fp32 -> bf16 copy + row sum-of-squares from the bf16 values.
__global__ __launch_bounds__(256) void k_convert(const float* __restrict__ X,
                                                 unsigned short* __restrict__ Xb,
                                                 float* __restrict__ sqv) {
    const int row = blockIdx.x;
    const int t = threadIdx.x;
    const float4* xr = (const float4*)(X + (size_t)row * KDIM);
    unsigned short* br = Xb + (size_t)row * KDIM;
    float acc = 0.f;
#pragma unroll
    for (int it = 0; it < 2; ++it) {
        int idx = t * 2 + it;
        float4 v = xr[idx];
        u16x4 b;
        b.x = f2bf(v.x); b.y = f2bf(v.y); b.z = f2bf(v.z); b.w = f2bf(v.w);
        float f0 = bf2f(b.x), f1 = bf2f(b.y), f2 = bf2f(b.z), f3 = bf2f(b.w);
        acc += f0 * f0 + f1 * f1 + f2 * f2 + f3 * f3;
        *(u16x4*)(br + idx * 4) = b;
    }
#pragma unroll
    for (int s = 32; s > 0; s >>= 1) acc += __shfl_xor(acc, s);
    __shared__ float red[4];
    const int lane = t & 63, wid = t >> 6;
    if (lane == 0) red[wid] = acc;
    __syncthreads();
    if (t == 0) sqv[row] = red[0] + red[1] + red[2] + red[3];
}

// Kernel 2: init per-row accumulators (d^2-space) + zero the output scalar.
__global__ __launch_bounds__(256) void k_init(unsigned* hp, unsigned* hn,
                                              unsigned* mor, unsigned* mir,
                                              float* out) {
    int i = blockIdx.x * 256 + threadIdx.x;
    hp[i] = 0u;
    hn[i] = 0x7F800000u;
    mor[i] = 0u;
    mir[i] = 0x7F800000u;
    if (i == 0) out[0] = 0.f;
}

// Kernel 3: 128x128-tile Gram GEMM, UPPER-TRIANGLE grid (528 blocks), the
// round-8 minimal-sync K-step, 48 KiB LDS (3 buffers) -> 3 blocks/CU so
// co-resident blocks fill each other's barrier stalls (m114 mechanism).
// Per K-tile: [vmcnt(4); s_barrier; 8 ds_read_b128; stage t+2; 16 MFMA].
// dist/masks symmetric + max/min idempotent -> off-diagonal blocks feed both
// row i (row-side) and row j (col-side) reductions, all in d^2 space.
__global__ __launch_bounds__(256, 3) void k_gemm(const unsigned short* __restrict__ Xb,
                                                 const float* __restrict__ sqv,
                                                 const int* __restrict__ ta,
                                                 const int* __restrict__ tb,
                                                 unsigned int* __restrict__ hp,
                                                 unsigned int* __restrict__ hn,
                                                 unsigned int* __restrict__ mor,
                                                 unsigned int* __restrict__ mir) {
    __shared__ char lds[3 * KTBUF];  // 48 KiB
    // triangle decode: block-row bi has (NB - bi) blocks, bj in [bi, NB)
    int rem = blockIdx.x;
    int bi = 0;
    while (rem >= NB - bi) { rem -= NB - bi; ++bi; }
    const int bj = bi + rem;

    const int t = threadIdx.x;
    const int lane = t & 63;
    const int w = t >> 6;        // wave 0..3
    const int wm = w >> 1;       // 0..1  (64-row half of A)
    const int wn = w & 1;        // 0..1  (64-col half of B)
    const int l15 = lane & 15;
    const int kg16 = (lane >> 4) * 16;  // k-group 16B slot within 64B row
    const char* xbase = (const char*)Xb;

    // swizzle is lane-constant for frag rows (offsets are multiples of 16)
    const int swz = ((l15 >> 1) & 3) << 4;
    const int akbase = (wm * 64 + l15) * 64 + (kg16 ^ swz);
    const int bkbase = AB_OFF + (wn * 64 + l15) * 64 + (kg16 ^ swz);

    f32x4 acc[4][4] = {};

    // Stage k-tile tt into buffer sb3: 4 gload_lds per thread (A q0,q1 +
    // B q0,q1). Wave-linear LDS dest; swizzle on the global source column.
#define STAGE(tt, sb3)                                                        \
    do {                                                                      \
        _Pragma("unroll")                                                     \
        for (int isb_ = 0; isb_ < 2; ++isb_) {                                \
            _Pragma("unroll")                                                 \
            for (int q_ = 0; q_ < 2; ++q_) {                                  \
                const int row_ = q_ * 64 + (t >> 2);                          \
                const int gr_ = (isb_ ? bj : bi) * BT + row_;                 \
                const char* gsrc_ = xbase + (size_t)gr_ * ROWB +              \
                                    (size_t)(tt) * 64 +                       \
                                    (((t & 3) * 16) ^ PHI(row_));             \
                char* ldst_ = lds + (sb3) * KTBUF + isb_ * AB_OFF +           \
                              row_ * 64 + (t & 3) * 16;                       \
                __builtin_amdgcn_global_load_lds(                             \
                    (const __attribute__((address_space(1))) void*)gsrc_,     \
                    (__attribute__((address_space(3))) void*)ldst_, 16, 0, 0);\
            }                                                                 \
        }                                                                     \
    } while (0)

    // prologue: tiles 0 -> buf0, 1 -> buf1 (8 loads/thread outstanding)
    STAGE(0, 0);
    STAGE(1, 1);

    int r3 = 0, s3 = 2;  // read buffer, stage buffer (t+2)
    for (int tk = 0; tk < NT; ++tk) {
        if (tk < NT - 1)
            asm volatile("s_waitcnt vmcnt(4)" ::: "memory");  // buf r3 resident
        else
            asm volatile("s_waitcnt vmcnt(0)" ::: "memory");
        __builtin_amdgcn_s_barrier();

        const char* buf = lds + r3 * KTBUF;
        // ---- all fragment reads first (before any LDS-writing vmem)
        bf16x8 af[4], bfr[4];
#pragma unroll
        for (int m = 0; m < 4; ++m)
            af[m] = *(const bf16x8*)(buf + akbase + m * 1024);
#pragma unroll
        for (int n = 0; n < 4; ++n)
            bfr[n] = *(const bf16x8*)(buf + bkbase + n * 1024);

        // ---- stage tile tk+2 (WAR-safe: that buffer's reads finished
        // before the barrier above)
        if (tk + 2 < NT) STAGE(tk + 2, s3);

        // ---- 16 MFMA; compiler inserts fine-grained lgkm waits
#pragma unroll
        for (int m = 0; m < 4; ++m)
#pragma unroll
            for (int n = 0; n < 4; ++n)
                acc[m][n] = MFMA16(af[m], bfr[n], acc[m][n]);

        r3 = (r3 == 2) ? 0 : r3 + 1;
        s3 = (s3 == 2) ? 0 : s3 + 1;
    }
#undef STAGE

    // ---- epilogue: d^2 + masks + row/col reductions (d^2-space) ----
    float sqj[4];
    int taj[4], tbj[4];
#pragma unroll
    for (int n = 0; n < 4; ++n) {
        int j = bj * BT + wn * 64 + n * 16 + l15;
        sqj[n] = sqv[j];
        taj[n] = ta[j];
        tbj[n] = tb[j];
    }
    const float INF = __uint_as_float(0x7F800000u);

    // column-side accumulators (per n, reduced over m/reg in-thread)
    float chp[4], chn[4], cmo[4], cmi[4];
#pragma unroll
    for (int n = 0; n < 4; ++n) {
        chp[n] = 0.f; chn[n] = INF; cmo[n] = 0.f; cmi[n] = INF;
    }

#pragma unroll
    for (int m = 0; m < 4; ++m) {
#pragma unroll
        for (int reg = 0; reg < 4; ++reg) {
            const int i = bi * BT + wm * 64 + m * 16 + (lane >> 4) * 4 + reg;
            const float sqi = sqv[i];
            const int tai = ta[i], tbi = tb[i];
            float vhp = 0.f, vhn = INF, vmo = 0.f, vmi = INF;
#pragma unroll
            for (int n = 0; n < 4; ++n) {
                float d2 = fmaxf(sqi + sqj[n] - 2.f * acc[m][n][reg], 1e-12f);
                bool ma = (tai == taj[n]), mb = (tbi == tbj[n]);
                if (ma && mb) {
                    vhp = fmaxf(vhp, d2);
                    chp[n] = fmaxf(chp[n], d2);
                } else if (ma != mb) {
                    vmo = fmaxf(vmo, d2);
                    vmi = fminf(vmi, d2);
                    cmo[n] = fmaxf(cmo[n], d2);
                    cmi[n] = fminf(cmi[n], d2);
                } else {
                    vhn = fminf(vhn, d2);
                    chn[n] = fminf(chn[n], d2);
                }
            }
#pragma unroll
            for (int s = 1; s < 16; s <<= 1) {
                vhp = fmaxf(vhp, __shfl_xor(vhp, s, 16));
                vhn = fminf(vhn, __shfl_xor(vhn, s, 16));
                vmo = fmaxf(vmo, __shfl_xor(vmo, s, 16));
                vmi = fminf(vmi, __shfl_xor(vmi, s, 16));
            }
            if (l15 == 0) {
                if (vhp > 0.f) atomicMax(&hp[i], __float_as_uint(vhp));
                if (vhn < INF) atomicMin(&hn[i], __float_as_uint(vhn));
                if (vmo > 0.f) {
                    atomicMax(&mor[i], __float_as_uint(vmo));
                    atomicMin(&mir[i], __float_as_uint(vmi));
                }
            }
        }
    }

    if (bi != bj) {
        // column-side: reduce across the 4 row-groups (lane>>4) via xor-16/32
#pragma unroll
        for (int n = 0; n < 4; ++n) {
            float a = chp[n], b = chn[n], c = cmo[n], d = cmi[n];
            a = fmaxf(a, __shfl_xor(a, 16)); a = fmaxf(a, __shfl_xor(a, 32));
            b = fminf(b, __shfl_xor(b, 16)); b = fminf(b, __shfl_xor(b, 32));
            c = fmaxf(c, __shfl_xor(c, 16)); c = fmaxf(c, __shfl_xor(c, 32));
            d = fminf(d, __shfl_xor(d, 16)); d = fminf(d, __shfl_xor(d, 32));
            if (lane < 16) {
                const int j = bj * BT + wn * 64 + n * 16 + lane;
                if (a > 0.f) atomicMax(&hp[j], __float_as_uint(a));
                if (b < INF) atomicMin(&hn[j], __float_as_uint(b));
                if (c > 0.f) {
                    atomicMax(&mor[j], __float_as_uint(c));
                    atomicMin(&mir[j], __float_as_uint(d));
                }
            }
        }
    }
}

// Kernel 4: final scalar loss (sqrt applied here; mor!=0 is the or-flag).
__global__ __launch_bounds__(256) void k_final(const unsigned* __restrict__ hp,
                                               const unsigned* __restrict__ hn,
                                               const unsigned* __restrict__ mor,
                                               const unsigned* __restrict__ mir,
                                               const int* __restrict__ epoch_p,
                                               float* __restrict__ out) {
    const int t = threadIdx.x;
    const int i = blockIdx.x * 256 + t;
    const bool eok = (*epoch_p > 50);
    const unsigned morb = mor[i];
    float fhp = sqrtf(__uint_as_float(hp[i]));
    float fhn = sqrtf(__uint_as_float(hn[i]));
    bool use_or = (morb != 0u) && eok;
    float sp = use_or ? sqrtf(__uint_as_float(morb)) : fhp;
    float sn = use_or ? sqrtf(__uint_as_float(mir[i])) : fhn;
    float s = fmaxf(0.f, fhp - fhn + 0.3f) + fmaxf(0.f, sp - fhn + 0.3f) +
              fmaxf(0.f, fhp - sn + 0.3f);
#pragma unroll
    for (int sh = 32; sh > 0; sh >>= 1) s += __shfl_xor(s, sh);
    __shared__ float red[4];
    const int lane = t & 63, wid = t >> 6;
    if (lane == 0) red[wid] = s;
    __syncthreads();
    if (t == 0)
        atomicAdd(out, (red[0] + red[1] + red[2] + red[3]) * (1.f / 4096.f));
}

extern "C" void kernel_launch(void* const* d_in, const int* in_sizes, int n_in,
                              void* d_out, int out_size, void* d_ws, size_t ws_size,
                              hipStream_t stream) {
    const float* X = (const float*)d_in[0];
    const int* ta = (const int*)d_in[1];
    const int* tb = (const int*)d_in[2];
    const int* epoch_p = (const int*)d_in[4];
    float* out = (float*)d_out;

    char* ws = (char*)d_ws;
    unsigned short* Xb = (unsigned short*)ws;  // 16 MB bf16 copy
    size_t off = (size_t)NROW * KDIM * sizeof(unsigned short);
    float* sqv = (float*)(ws + off); off += (size_t)NROW * 4;
    unsigned* hp = (unsigned*)(ws + off); off += (size_t)NROW * 4;
    unsigned* hn = (unsigned*)(ws + off); off += (size_t)NROW * 4;
    unsigned* mor = (unsigned*)(ws + off); off += (size_t)NROW * 4;
    unsigned* mir = (unsigned*)(ws + off); off += (size_t)NROW * 4;

    k_convert<<<NROW, 256, 0, stream>>>(X, Xb, sqv);
    k_init<<<NROW / 256, 256, 0, stream>>>(hp, hn, mor, mir, out);
    k_gemm<<<(NB * (NB + 1)) / 2, 256, 0, stream>>>(Xb, sqv, ta, tb,
                                                    hp, hn, mor, mir);
    k_final<<<NROW / 256, 256, 0, stream>>>(hp, hn, mor, mir, epoch_p, out);
}